// Round 1
// baseline (514.199 us; speedup 1.0000x reference)
//
#include <hip/hip_runtime.h>

#define N_NODES 100000
#define N_EDGES 1250000
#define D 64
#define ED 32

// Wave-per-edge: lane d computes output dim d of the edge embedding,
// adds gathered x[row][d], atomically accumulates into agg[col][d].
__global__ void __launch_bounds__(256) edge_scatter_k(
    const float* __restrict__ x,
    const int* __restrict__ ei,     // [2][E] int32
    const float* __restrict__ ea,   // [E][32]
    const float* __restrict__ ew,   // [64][32]
    const float* __restrict__ eb,   // [64]
    float* __restrict__ agg,        // [N][64] (pre-zeroed; = d_out)
    float* __restrict__ deg)        // [N]     (pre-zeroed; in d_ws)
{
    const int lane = threadIdx.x & 63;
    const int wid  = blockIdx.x * (blockDim.x >> 6) + (threadIdx.x >> 6);
    const int nw   = gridDim.x * (blockDim.x >> 6);

    // Per-lane row of edge_w: lane d holds edge_w[d][0..31] in VGPRs.
    float w[ED];
#pragma unroll
    for (int k = 0; k < ED; ++k) w[k] = ew[lane * ED + k];
    const float b = eb[lane];

    for (int e = wid; e < N_EDGES; e += nw) {
        const int r = ei[e];            // source node
        const int c = ei[N_EDGES + e];  // destination node
        const float4* ea4 = (const float4*)(ea + (size_t)e * ED);
        float acc = b;
#pragma unroll
        for (int q = 0; q < ED / 4; ++q) {
            // wave-uniform address -> single 16B request, broadcast to lanes
            float4 v = ea4[q];
            acc = fmaf(v.x, w[4 * q + 0], acc);
            acc = fmaf(v.y, w[4 * q + 1], acc);
            acc = fmaf(v.z, w[4 * q + 2], acc);
            acc = fmaf(v.w, w[4 * q + 3], acc);
        }
        acc += x[(size_t)r * D + lane];          // gathered source feature
        atomicAdd(&agg[(size_t)c * D + lane], acc);  // coalesced 256B wave-atomic
        if (lane == 0) atomicAdd(&deg[c], 1.0f);
    }
}

// Wave-per-node: out[n][d] = (1/max(deg,1)) * dot(agg[n][:], lin_w[d][:]) + lin_b[d]
// Runs in-place on agg (= d_out): all reads of row n feed acc before the store.
__global__ void __launch_bounds__(256) node_linear_k(
    float* __restrict__ agg,        // [N][64] in, overwritten with result
    const float* __restrict__ deg,  // [N]
    const float* __restrict__ lw,   // [64][64]
    const float* __restrict__ lb)   // [64]
{
    const int lane = threadIdx.x & 63;
    const int wid  = blockIdx.x * (blockDim.x >> 6) + (threadIdx.x >> 6);
    const int nw   = gridDim.x * (blockDim.x >> 6);

    float w[D];
#pragma unroll
    for (int k = 0; k < D; ++k) w[k] = lw[lane * D + k];
    const float b = lb[lane];

    for (int n = wid; n < N_NODES; n += nw) {
        const float inv = 1.0f / fmaxf(deg[n], 1.0f);
        const float4* a4 = (const float4*)(agg + (size_t)n * D);
        float dot = 0.0f;
#pragma unroll
        for (int q = 0; q < D / 4; ++q) {
            float4 v = a4[q];   // wave-uniform, L1/L2 broadcast
            dot = fmaf(v.x, w[4 * q + 0], dot);
            dot = fmaf(v.y, w[4 * q + 1], dot);
            dot = fmaf(v.z, w[4 * q + 2], dot);
            dot = fmaf(v.w, w[4 * q + 3], dot);
        }
        agg[(size_t)n * D + lane] = fmaf(inv, dot, b);
    }
}

extern "C" void kernel_launch(void* const* d_in, const int* in_sizes, int n_in,
                              void* d_out, int out_size, void* d_ws, size_t ws_size,
                              hipStream_t stream) {
    const float* x  = (const float*)d_in[0];
    const int*   ei = (const int*)d_in[1];
    const float* ea = (const float*)d_in[2];
    const float* lw = (const float*)d_in[3];
    const float* lb = (const float*)d_in[4];
    const float* ew = (const float*)d_in[5];
    const float* eb = (const float*)d_in[6];

    float* agg = (float*)d_out;   // reuse output buffer as the aggregation buffer
    float* deg = (float*)d_ws;    // N floats of scratch

    hipMemsetAsync(agg, 0, (size_t)N_NODES * D * sizeof(float), stream);
    hipMemsetAsync(deg, 0, (size_t)N_NODES * sizeof(float), stream);

    edge_scatter_k<<<2048, 256, 0, stream>>>(x, ei, ea, ew, eb, agg, deg);
    node_linear_k<<<1024, 256, 0, stream>>>(agg, deg, lw, lb);
}